// Round 10
// baseline (343.930 us; speedup 1.0000x reference)
//
#include <hip/hip_runtime.h>
#include <hip/hip_bf16.h>

// Shapes (fixed by the problem)
#define NB 2
#define NN 4096
#define NC 1024
#define NH 16
#define ND 64
#define NM (NB*NN)          // 8192 rows
#define NK 1024             // inner dim of both GEMMs
#define J_QKV 3072
// D^-0.5 * log2(e): folded into q at LN time so softmax runs in exp2 domain.
// Post-LN rows have ||q||,||k|| <= 8  =>  |score_exp2| <= 8*8*0.1803 = 11.54,
// so exp2(score) in [2^-11.6, 2^11.6]: fp32-safe with NO max subtraction.
#define QSCALE 0.18033688011112042f

typedef unsigned short u16;
typedef unsigned int   u32;
typedef __attribute__((ext_vector_type(8)))  __bf16 bf16x8;
typedef __attribute__((ext_vector_type(4)))  float  f32x4;
typedef __attribute__((ext_vector_type(16))) float  f32x16;

__device__ __forceinline__ u16 f2bf(float f) {
    unsigned int i = __builtin_bit_cast(unsigned int, f);
    unsigned int lsb = (i >> 16) & 1u;
    i += 0x7fffu + lsb;          // RNE
    return (u16)(i >> 16);
}
__device__ __forceinline__ float fast_exp2(float x) {
#if __has_builtin(__builtin_amdgcn_exp2f)
    return __builtin_amdgcn_exp2f(x);   // v_exp_f32 = 2^x
#else
    return exp2f(x);
#endif
}
// pack 2 fp32 -> 1 u32 of 2 bf16 (low = first arg).  NOTE: no builtin on
// gfx950 (m240); inline asm emits the single-instruction v_cvt_pk_bf16_f32.
__device__ __forceinline__ u32 pkbf(float a, float b) {
    u32 r;
    asm("v_cvt_pk_bf16_f32 %0, %1, %2" : "=v"(r) : "v"(a), "v"(b));
    return r;
}
// v_permlane32_swap_b32: returns {r0,r1} with r0 = {a.lo half, b.lo half},
// r1 = {a.hi half, b.hi half}. Used to assemble PV A-fragments in-register.
typedef struct { u32 x, y; } u32pair;
__device__ __forceinline__ u32pair swap32(u32 a, u32 b) {
#if __has_builtin(__builtin_amdgcn_permlane32_swap)
    auto r = __builtin_amdgcn_permlane32_swap((int)a, (int)b, false, false);
    u32pair o; o.x = (u32)r[0]; o.y = (u32)r[1]; return o;
#else
    const bool hi = (threadIdx.x & 32) != 0;
    u32 as = (u32)__shfl_xor((int)a, 32);
    u32 bs = (u32)__shfl_xor((int)b, 32);
    u32pair o; o.x = hi ? bs : a; o.y = hi ? b : as; return o;
#endif
}

// Async global->LDS 16B copy (global_load_lds_dwordx4).
__device__ __forceinline__ void glds16(const u16* g, u16* l) {
    __builtin_amdgcn_global_load_lds(
        (const __attribute__((address_space(1))) u32*)g,
        (__attribute__((address_space(3))) u32*)l, 16, 0, 0);
}

// ---------------------------------------------------------------------------
// Fused fp32 -> bf16 convert for all three buffers (one launch instead of 3).
// Segment sizes in 2048-elem blocks: x=4096, qkv_w=1536, proj_w=512.
// ---------------------------------------------------------------------------
__global__ __launch_bounds__(256) void cvt3(
    const float* __restrict__ a, u16* __restrict__ oa,
    const float* __restrict__ b, u16* __restrict__ ob,
    const float* __restrict__ c, u16* __restrict__ oc)
{
    const int blk = blockIdx.x;
    const float* src; u16* dst; size_t off;
    if (blk < 4096)      { src = a; dst = oa; off = (size_t)blk * 2048; }
    else if (blk < 5632) { src = b; dst = ob; off = (size_t)(blk - 4096) * 2048; }
    else                 { src = c; dst = oc; off = (size_t)(blk - 5632) * 2048; }
    const size_t i = off + (size_t)threadIdx.x * 8;
    const float4 va = *(const float4*)(src + i);
    const float4 vb = *(const float4*)(src + i + 4);
    union { u16 h[8]; uint4 v; } u;
    u.h[0] = f2bf(va.x); u.h[1] = f2bf(va.y); u.h[2] = f2bf(va.z); u.h[3] = f2bf(va.w);
    u.h[4] = f2bf(vb.x); u.h[5] = f2bf(vb.y); u.h[6] = f2bf(vb.z); u.h[7] = f2bf(vb.w);
    *(uint4*)(dst + i) = u.v;
}

// ---------------------------------------------------------------------------
// NT GEMM, m97 recipe + BK=64 + XCD swizzle (R7-verified loop) + LDS-bounce
// MODE-0 epilogue (R9).  OCC: min-waves/EU -> blocks/CU; QKV tries 4 (VGPR
// cap 128; K-loop peak est. ~112), proj stays 3.
// MODE 0: fused per-head LayerNorm (q scaled by QSCALE) + scatter bf16 to
//         qkv ws [3][B][H][N][D].  MODE 1: fp32 linear [m][1024].
// ---------------------------------------------------------------------------
template<int MODE, int NJB, int OCC>
__global__ __launch_bounds__(256, OCC) void gemm_nt(
    const u16* __restrict__ A, const u16* __restrict__ W,
    const float* __restrict__ bias,
    const float* __restrict__ qw, const float* __restrict__ qb,
    const float* __restrict__ kw, const float* __restrict__ kb,
    void* __restrict__ outv)
{
    // sm[0]=A klo, sm[1]=A khi, sm[2]=B klo, sm[3]=B khi (32 KB total).
    // After the K-loop, reused as bounce[128][128] u16 for MODE 0.
    __shared__ __align__(16) u16 sm[4][128][32];
    const int t = threadIdx.x;
    const int w = t >> 6, lane = t & 63;
    // XCD-chunked bijective swizzle, m-fastest within chunk.
    const int nb   = blockIdx.x;
    const int cpx  = gridDim.x >> 3;
    const int nb2  = (nb & 7) * cpx + (nb >> 3);
    const int chunk = nb2 / cpx;
    const int c     = nb2 - chunk * cpx;
    const int jb  = (c >> 3) * 128;
    const int m0  = (chunk * 8 + (c & 7)) * 128;
    const int wr = (w >> 1) * 64, wc = (w & 1) * 64;
    // staging: thread t covers rows t>>2 and 64+(t>>2), k-cols (t&3)*8..+7
    const int srow = t >> 2, skc = (t & 3) * 8;
    const u16* ap0 = A + (size_t)(m0 + srow) * NK + skc;
    const u16* ap1 = ap0 + (size_t)64 * NK;
    const u16* wp0 = W + (size_t)(jb + srow) * NK + skc;
    const u16* wp1 = wp0 + (size_t)64 * NK;
    u16* asl0 = &sm[0][srow][skc];    u16* asl1 = &sm[0][srow + 64][skc];
    u16* ash0 = &sm[1][srow][skc];    u16* ash1 = &sm[1][srow + 64][skc];
    u16* bsl0 = &sm[2][srow][skc];    u16* bsl1 = &sm[2][srow + 64][skc];
    u16* bsh0 = &sm[3][srow][skc];    u16* bsh1 = &sm[3][srow + 64][skc];
    const int fm = lane & 15, fk = 8 * (lane >> 4);
    f32x4 acc[4][4];
    #pragma unroll
    for (int i = 0; i < 4; ++i)
        #pragma unroll
        for (int j = 0; j < 4; ++j) acc[i][j] = (f32x4){0.f, 0.f, 0.f, 0.f};

    for (int kt = 0; kt < NK / 64; ++kt) {
        const int ko = kt * 64;
        glds16(ap0 + ko, asl0);
        glds16(ap1 + ko, asl1);
        glds16(ap0 + ko + 32, ash0);
        glds16(ap1 + ko + 32, ash1);
        glds16(wp0 + ko, bsl0);
        glds16(wp1 + ko, bsl1);
        glds16(wp0 + ko + 32, bsh0);
        glds16(wp1 + ko + 32, bsh1);
        __syncthreads();               // drains vmcnt (glds) before reads
        {   // ---- lo k-half ----
            bf16x8 af[4], bfr[4];
            #pragma unroll
            for (int i = 0; i < 4; ++i) af[i]  = *(const bf16x8*)&sm[0][wr + 16 * i + fm][fk];
            #pragma unroll
            for (int j = 0; j < 4; ++j) bfr[j] = *(const bf16x8*)&sm[2][wc + 16 * j + fm][fk];
            #pragma unroll
            for (int i = 0; i < 4; ++i)
                #pragma unroll
                for (int j = 0; j < 4; ++j)
                    acc[i][j] = __builtin_amdgcn_mfma_f32_16x16x32_bf16(af[i], bfr[j], acc[i][j], 0, 0, 0);
        }
        {   // ---- hi k-half ----
            bf16x8 af[4], bfr[4];
            #pragma unroll
            for (int i = 0; i < 4; ++i) af[i]  = *(const bf16x8*)&sm[1][wr + 16 * i + fm][fk];
            #pragma unroll
            for (int j = 0; j < 4; ++j) bfr[j] = *(const bf16x8*)&sm[3][wc + 16 * j + fm][fk];
            #pragma unroll
            for (int i = 0; i < 4; ++i)
                #pragma unroll
                for (int j = 0; j < 4; ++j)
                    acc[i][j] = __builtin_amdgcn_mfma_f32_16x16x32_bf16(af[i], bfr[j], acc[i][j], 0, 0, 0);
        }
        __syncthreads();               // WAR before next kt's glds
    }
    // ---- epilogue ----
    const int c16 = lane & 15;
    float bv[4];
    #pragma unroll
    for (int j = 0; j < 4; ++j) bv[j] = bias[jb + wc + 16 * j + c16];
    #pragma unroll
    for (int i = 0; i < 4; ++i)
        #pragma unroll
        for (int j = 0; j < 4; ++j)
            #pragma unroll
            for (int r = 0; r < 4; ++r) acc[i][j][r] += bv[j];
    if (MODE == 0) {
        const int s = jb >> 10;            // 0=q, 1=k, 2=v (uniform per block)
        if (s < 2) {
            const float* lw = s ? kw : qw;
            const float* lb = s ? kb : qb;
            float lwv[4], lbv[4];
            #pragma unroll
            for (int j = 0; j < 4; ++j) {
                lwv[j] = lw[16 * j + c16]; lbv[j] = lb[16 * j + c16];
            }
            #pragma unroll
            for (int i = 0; i < 4; ++i)
                #pragma unroll
                for (int r = 0; r < 4; ++r) {
                    float sum = acc[i][0][r] + acc[i][1][r] + acc[i][2][r] + acc[i][3][r];
                    #pragma unroll
                    for (int off = 1; off < 16; off <<= 1) sum += __shfl_xor(sum, off);
                    const float mu = sum * (1.0f / 64.0f);
                    float v2 = 0.f;
                    #pragma unroll
                    for (int j = 0; j < 4; ++j) { const float dd = acc[i][j][r] - mu; v2 += dd * dd; }
                    #pragma unroll
                    for (int off = 1; off < 16; off <<= 1) v2 += __shfl_xor(v2, off);
                    const float rstd = rsqrtf(v2 * (1.0f / 64.0f) + 1e-5f);
                    #pragma unroll
                    for (int j = 0; j < 4; ++j) {
                        float y = (acc[i][j][r] - mu) * rstd * lwv[j] + lbv[j];
                        if (s == 0) y *= QSCALE;
                        acc[i][j][r] = y;
                    }
                }
        }
        // ---- bounce acc -> LDS [128][128] u16 (staging arrays dead) ----
        u16 (*bounce)[128] = (u16 (*)[128])sm;
        const int r0 = 4 * (lane >> 4);
        #pragma unroll
        for (int i = 0; i < 4; ++i)
            #pragma unroll
            for (int r = 0; r < 4; ++r)
                #pragma unroll
                for (int j = 0; j < 4; ++j)
                    bounce[wr + 16 * i + r0 + r][wc + 16 * j + c16] = f2bf(acc[i][j][r]);
        __syncthreads();
        // ---- coalesced store: wave covers 8 consecutive rows x 128B = 1KB ----
        u16* out = (u16*)outv;
        const int l8 = lane >> 3, k8 = lane & 7;
        #pragma unroll
        for (int ch = 0; ch < 2; ++ch) {
            const int col0 = jb + ch * 64;
            const int ss = col0 >> 10, hh = (col0 >> 6) & 15;
            #pragma unroll
            for (int g = 0; g < 4; ++g) {
                const int rr = 32 * w + 8 * g + l8;
                const int row = m0 + rr;
                const int b_ = row >> 12, n = row & 4095;
                const uint4 v = *(const uint4*)&bounce[rr][ch * 64 + k8 * 8];
                *(uint4*)&out[((((size_t)ss * NB + b_) * NH + hh) * NN + n) * ND + k8 * 8] = v;
            }
        }
    } else {
        float* out = (float*)outv;
        const int r0 = 4 * (lane >> 4);
        #pragma unroll
        for (int i = 0; i < 4; ++i)
            #pragma unroll
            for (int r = 0; r < 4; ++r) {
                const int row = m0 + wr + 16 * i + r0 + r;
                #pragma unroll
                for (int j = 0; j < 4; ++j)
                    out[(size_t)row * NC + jb + wc + 16 * j + c16] = acc[i][j][r];
            }
    }
}

// ---------------------------------------------------------------------------
// MFMA flash attention (R4-verified structure) + ones-MFMA softmax denominator:
// L[s] = sum_k P[q,k] computed by mfma(pa, ONES) -- same C-row layout as O, so
// inv = 1/L[s][r] directly (replaces 64 VALU adds/iter + epilogue shuffles;
// also makes denominator use the same bf16-rounded P as the numerator).
// Block = 4 waves; wave = 64 q-rows (2 x 32-row q-sets); K-blocks of 64 keys.
// DOUBLE-BUFFERED Ks/Vt, ONE barrier/iter, T14 staging, swapped QK^T,
// in-register P via asm cvt_pk + permlane32_swap.
// ---------------------------------------------------------------------------
__global__ __launch_bounds__(256, 2) void attn_mfma(
    const u16* __restrict__ qkv, u16* __restrict__ aout)
{
    __shared__ __align__(16) u16 Ks[2][64][72];   // K-block   [key][d]   18.4 KB
    __shared__ __align__(16) u16 Vt[2][64][72];   // V-block^T [d][key]   18.4 KB
    const int bid  = blockIdx.x;
    const int qblk = bid & 15;
    const int bh   = bid >> 4;
    const int b = bh >> 4, hh = bh & 15;
    const size_t plane = (size_t)NB * NH * NN * ND;
    const size_t base  = ((size_t)(b * NH + hh)) * NN * ND;
    const u16* qp = qkv + base;
    const u16* kp = qkv + plane + base;
    const u16* vp = qkv + 2 * plane + base;
    const int t = threadIdx.x, w = t >> 6, lane = t & 63;
    const int half = lane >> 5, m32 = lane & 31;
    const int q0 = qblk * 256 + 64 * w;           // this wave's 64 q-rows

    // Q as B-operand (col = q = lane&31, k = d)
    bf16x8 qf[2][4];
    #pragma unroll
    for (int s = 0; s < 2; ++s) {
        const u16* qrow = qp + (size_t)(q0 + 32 * s + m32) * ND + 8 * half;
        #pragma unroll
        for (int kt = 0; kt < 4; ++kt) qf[s][kt] = *(const bf16x8*)(qrow + 16 * kt);
    }
    f32x16 O[2][2], L[2], z;
    #pragma unroll
    for (int r = 0; r < 16; ++r) {
        O[0][0][r] = 0.f; O[0][1][r] = 0.f;
        O[1][0][r] = 0.f; O[1][1][r] = 0.f;
        L[0][r] = 0.f;    L[1][r] = 0.f;    z[r] = 0.f;
    }
    // all-ones bf16 B-operand for the denominator MFMA (layout-independent)
    union { u32 wd[4]; bf16x8 f; } ONE1;
    #pragma unroll
    for (int i = 0; i < 4; ++i) ONE1.wd[i] = 0x3F803F80u;

    const int dgK = 16 * w;                     // K staging: key=lane, 16 d/thread
    const int kp2 = t & 31, dgV = (t >> 5) * 8; // V staging: 2 keys x 8 d/thread
    const u16* ksrc = kp + (size_t)lane * ND + dgK;
    const u16* vsrc = vp + (size_t)(2 * kp2) * ND + dgV;

    uint4 kr0, kr1, vre, vro;                   // staged regs for next K-block
    // prologue: stage block 0 into buffer 0
    kr0 = *(const uint4*)(ksrc);
    kr1 = *(const uint4*)(ksrc + 8);
    vre = *(const uint4*)(vsrc);
    vro = *(const uint4*)(vsrc + ND);
    {
        *(uint4*)&Ks[0][lane][dgK]     = kr0;
        *(uint4*)&Ks[0][lane][dgK + 8] = kr1;
        const u32* ew = (const u32*)&vre;
        const u32* ow = (const u32*)&vro;
        #pragma unroll
        for (int d = 0; d < 4; ++d) {       // v_perm_b32 pair-pack transpose
            u32 lo = __builtin_amdgcn_perm(ow[d], ew[d], 0x05040100u);
            u32 hi = __builtin_amdgcn_perm(ow[d], ew[d], 0x07060302u);
            *(u32*)&Vt[0][dgV + 2 * d][2 * kp2]     = lo;
            *(u32*)&Vt[0][dgV + 2 * d + 1][2 * kp2] = hi;
        }
    }
    __syncthreads();

    union W8 { u32 wd[4]; bf16x8 f; };

    for (int kb = 0; kb < NN / 64; ++kb) {
        const int cur = kb & 1, nxt = cur ^ 1;
        const bool more = (kb + 1) < (NN / 64);
        if (more) {   // issue next block's global loads early (hide under compute)
            const u16* ks2 = ksrc + (size_t)(kb + 1) * 64 * ND;
            kr0 = *(const uint4*)ks2;
            kr1 = *(const uint4*)(ks2 + 8);
            const u16* vs2 = vsrc + (size_t)(kb + 1) * 64 * ND;
            vre = *(const uint4*)vs2;
            vro = *(const uint4*)(vs2 + ND);
        }
        // ---- QK (s0): S^T = K . Q^T, col=lane&31=q, row=key pattern ----
        f32x16 sT0[2], sT1[2];
        __builtin_amdgcn_s_setprio(1);
        {
            bf16x8 k0 = *(const bf16x8*)&Ks[cur][m32][8 * half];
            bf16x8 k1 = *(const bf16x8*)&Ks[cur][32 + m32][8 * half];
            sT0[0] = __builtin_amdgcn_mfma_f32_32x32x16_bf16(k0, qf[0][0], z, 0, 0, 0);
            sT0[1] = __builtin_amdgcn_mfma_f32_32x32x16_bf16(k1, qf[0][0], z, 0, 0, 0);
        }
        #pragma unroll
        for (int kt = 1; kt < 4; ++kt) {
            bf16x8 k0 = *(const bf16x8*)&Ks[cur][m32][16 * kt + 8 * half];
            bf16x8 k1 = *(const bf16x8*)&Ks[cur][32 + m32][16 * kt + 8 * half];
            sT0[0] = __builtin_amdgcn_mfma_f32_32x32x16_bf16(k0, qf[0][kt], sT0[0], 0, 0, 0);
            sT0[1] = __builtin_amdgcn_mfma_f32_32x32x16_bf16(k1, qf[0][kt], sT0[1], 0, 0, 0);
        }
        // ---- QK (s1): issues while sT0 chain drains ----
        {
            bf16x8 k0 = *(const bf16x8*)&Ks[cur][m32][8 * half];
            bf16x8 k1 = *(const bf16x8*)&Ks[cur][32 + m32][8 * half];
            sT1[0] = __builtin_amdgcn_mfma_f32_32x32x16_bf16(k0, qf[1][0], z, 0, 0, 0);
            sT1[1] = __builtin_amdgcn_mfma_f32_32x32x16_bf16(k1, qf[1][0], z, 0, 0, 0);
        }
        #pragma unroll
        for (int kt = 1; kt < 4; ++kt) {
            bf16x8 k0 = *(const bf16x8*)&Ks[cur][m32][16 * kt + 8 * half];
            bf16x8 k1 = *(const bf16x8*)&Ks[cur][32 + m32][16 * kt + 8 * half];
            sT1[0] = __builtin_amdgcn_mfma_f32_32x32x16_bf16(k0, qf[1][kt], sT1[0], 0, 0, 0);
            sT1[1] = __builtin_amdgcn_mfma_f32_32x32x16_bf16(k1, qf[1][kt], sT1[1], 0, 0, 0);
        }
        __builtin_amdgcn_s_setprio(0);
        // ---- SM (s0): exp2 + cvt_pk + permlane, under QK(s1) MFMAs ----
        W8 pa0[4], pa1[4];
        #pragma unroll
        for (int kh = 0; kh < 2; ++kh) {
            float p[16];
            #pragma unroll
            for (int r = 0; r < 16; ++r) p[r] = fast_exp2(sT0[kh][r]);
            u32 c[4][2];
            #pragma unroll
            for (int g = 0; g < 4; ++g) {
                c[g][0] = pkbf(p[4 * g + 0], p[4 * g + 1]);
                c[g][1] = pkbf(p[4 * g + 2], p[4 * g + 3]);
            }
            #pragma unroll
            for (int par = 0; par < 2; ++par) {
                u32pair wA = swap32(c[2 * par][0], c[2 * par + 1][0]);
                u32pair wB = swap32(c[2 * par][1], c[2 * par + 1][1]);
                const int kt = 2 * kh + par;
                pa0[kt].wd[0] = wA.x;   // keys +0,+1 (from low-half lane)
                pa0[kt].wd[1] = wB.x;   // keys +2,+3
                pa0[kt].wd[2] = wA.y;   // keys +4,+5 (from high-half lane)
                pa0[kt].wd[3] = wB.y;   // keys +6,+7
            }
        }
        // ---- PV (s0) + denominator L[0] ----
        __builtin_amdgcn_s_setprio(1);
        #pragma unroll
        for (int kt = 0; kt < 4; ++kt) {
            bf16x8 v0 = *(const bf16x8*)&Vt[cur][m32][16 * kt + 8 * half];
            bf16x8 v1 = *(const bf16x8*)&Vt[cur][32 + m32][16 * kt + 8 * half];
            O[0][0] = __builtin_amdgcn_mfma_f32_32x32x16_bf16(pa0[kt].f, v0, O[0][0], 0, 0, 0);
            O[0][1] = __builtin_amdgcn_mfma_f32_32x32x16_bf16(pa0[kt].f, v1, O[0][1], 0, 0, 0);
            L[0]    = __builtin_amdgcn_mfma_f32_32x32x16_bf16(pa0[kt].f, ONE1.f, L[0], 0, 0, 0);
        }
        __builtin_amdgcn_s_setprio(0);
        // ---- SM (s1): under PV(s0) MFMAs ----
        #pragma unroll
        for (int kh = 0; kh < 2; ++kh) {
            float p[16];
            #pragma unroll
            for (int r = 0; r < 16; ++r) p[r] = fast_exp2(sT1[kh][r]);
            u32 c[4][2];
            #pragma unroll
            for (int g = 0; g < 4; ++g) {
                c[g][0] = pkbf(p[4 * g + 0], p[4 * g + 1]);
                c[g][1] = pkbf(p[4 * g + 2], p[4 * g + 3]);
            }
            #pragma unroll
            for (int par = 0; par < 2; ++par) {
                u32pair wA = swap32(c[2 * par][0], c[2 * par + 1][0]);
                u32pair wB = swap32(c[2 * par][1], c[2 * par + 1][1]);
                const int kt = 2 * kh + par;
                pa1[kt].wd[0] = wA.x;
                pa1[kt].wd[1] = wB.x;
                pa1[kt].wd[2] = wA.y;
                pa1[kt].wd[3] = wB.y;
            }
        }
        // ---- PV (s1) + denominator L[1] ----
        __builtin_amdgcn_s_setprio(1);
        #pragma unroll
        for (int kt = 0; kt < 4; ++kt) {
            bf16x8 v0 = *(const bf16x8*)&Vt[cur][m32][16 * kt + 8 * half];
            bf16x8 v1 = *(const bf16x8*)&Vt[cur][32 + m32][16 * kt + 8 * half];
            O[1][0] = __builtin_amdgcn_mfma_f32_32x32x16_bf16(pa1[kt].f, v0, O[1][0], 0, 0, 0);
            O[1][1] = __builtin_amdgcn_mfma_f32_32x32x16_bf16(pa1[kt].f, v1, O[1][1], 0, 0, 0);
            L[1]    = __builtin_amdgcn_mfma_f32_32x32x16_bf16(pa1[kt].f, ONE1.f, L[1], 0, 0, 0);
        }
        __builtin_amdgcn_s_setprio(0);
        // ---- stage next block into nxt buffer; ONE barrier per iteration ----
        if (more) {
            *(uint4*)&Ks[nxt][lane][dgK]     = kr0;
            *(uint4*)&Ks[nxt][lane][dgK + 8] = kr1;
            const u32* ew = (const u32*)&vre;
            const u32* ow = (const u32*)&vro;
            #pragma unroll
            for (int d = 0; d < 4; ++d) {
                u32 lo = __builtin_amdgcn_perm(ow[d], ew[d], 0x05040100u);
                u32 hi = __builtin_amdgcn_perm(ow[d], ew[d], 0x07060302u);
                *(u32*)&Vt[nxt][dgV + 2 * d][2 * kp2]     = lo;
                *(u32*)&Vt[nxt][dgV + 2 * d + 1][2 * kp2] = hi;
            }
            __syncthreads();   // nxt writes visible; cur reads done for all waves
        }
    }
    // epilogue: L has the SAME C-row layout as O -> direct per-reg normalize.
    #pragma unroll
    for (int s = 0; s < 2; ++s) {
        #pragma unroll
        for (int r = 0; r < 16; ++r) {
            const int qq = (r & 3) + 8 * (r >> 2) + 4 * half;   // O-row for this reg
            const float inv = 1.0f / L[s][r];
            const int row = q0 + 32 * s + qq;
            u16* dst = aout + ((size_t)(b * NN + row)) * NC + hh * 64;
            dst[m32]      = f2bf(O[s][0][r] * inv);
            dst[32 + m32] = f2bf(O[s][1][r] * inv);
        }
    }
}

// ---------------------------------------------------------------------------
extern "C" void kernel_launch(void* const* d_in, const int* in_sizes, int n_in,
                              void* d_out, int out_size, void* d_ws, size_t ws_size,
                              hipStream_t stream) {
    const float* x     = (const float*)d_in[0];
    const float* qkv_w = (const float*)d_in[1];
    const float* qkv_b = (const float*)d_in[2];
    const float* q_nw  = (const float*)d_in[3];
    const float* q_nb  = (const float*)d_in[4];
    const float* k_nw  = (const float*)d_in[5];
    const float* k_nb  = (const float*)d_in[6];
    const float* p_w   = (const float*)d_in[7];
    const float* p_b   = (const float*)d_in[8];
    float* out = (float*)d_out;               // fp32 output
    // ws layout (u16 elements):
    //   qkv   [3][B][H][N][D]                              48 MB
    //   x_bf / attn_o (aliased: x_bf dead after QKV GEMM)  16.8 MB
    //   w_bf  qkv_w bf16                                    6.3 MB
    //   pw_bf proj_w bf16                                   2.1 MB
    u16* qkv    = (u16*)d_ws;
    u16* x_bf   = qkv + (size_t)3 * NB * NH * NN * ND;
    u16* attn_o = x_bf;                        // alias
    u16* w_bf   = x_bf + (size_t)NM * NC;
    u16* pw_bf  = w_bf + (size_t)J_QKV * NK;

    cvt3<<<6144, 256, 0, stream>>>(x, x_bf, qkv_w, w_bf, p_w, pw_bf);

    // 1D grids (both % 8 == 0) with in-kernel bijective XCD-chunk swizzle.
    gemm_nt<0, J_QKV / 128, 4><<<(J_QKV / 128) * (NM / 128), 256, 0, stream>>>(
        x_bf, w_bf, qkv_b, q_nw, q_nb, k_nw, k_nb, qkv);
    attn_mfma<<<NB * NH * (NN / 256), 256, 0, stream>>>(qkv, attn_o);
    gemm_nt<1, NC / 128, 3><<<(NC / 128) * (NM / 128), 256, 0, stream>>>(
        attn_o, pw_bf, p_b, q_nw, q_nb, k_nw, k_nb, out);
}

// Round 11
// 327.804 us; speedup vs baseline: 1.0492x; 1.0492x over previous
//
#include <hip/hip_runtime.h>
#include <hip/hip_bf16.h>

// Shapes (fixed by the problem)
#define NB 2
#define NN 4096
#define NC 1024
#define NH 16
#define ND 64
#define NM (NB*NN)          // 8192 rows
#define NK 1024             // inner dim of both GEMMs
#define J_QKV 3072
// D^-0.5 * log2(e): folded into q at LN time so softmax runs in exp2 domain.
// Post-LN rows have ||q||,||k|| <= 8  =>  |score_exp2| <= 8*8*0.1803 = 11.54,
// so exp2(score) in [2^-11.6, 2^11.6]: fp32-safe with NO max subtraction.
#define QSCALE 0.18033688011112042f

typedef unsigned short u16;
typedef unsigned int   u32;
typedef __attribute__((ext_vector_type(8)))  __bf16 bf16x8;
typedef __attribute__((ext_vector_type(4)))  float  f32x4;
typedef __attribute__((ext_vector_type(16))) float  f32x16;

__device__ __forceinline__ u16 f2bf(float f) {
    unsigned int i = __builtin_bit_cast(unsigned int, f);
    unsigned int lsb = (i >> 16) & 1u;
    i += 0x7fffu + lsb;          // RNE
    return (u16)(i >> 16);
}
__device__ __forceinline__ float fast_exp2(float x) {
#if __has_builtin(__builtin_amdgcn_exp2f)
    return __builtin_amdgcn_exp2f(x);   // v_exp_f32 = 2^x
#else
    return exp2f(x);
#endif
}
// pack 2 fp32 -> 1 u32 of 2 bf16 (low = first arg).  NOTE: no builtin on
// gfx950 (m240); inline asm emits the single-instruction v_cvt_pk_bf16_f32.
__device__ __forceinline__ u32 pkbf(float a, float b) {
    u32 r;
    asm("v_cvt_pk_bf16_f32 %0, %1, %2" : "=v"(r) : "v"(a), "v"(b));
    return r;
}
// v_permlane32_swap_b32: returns {r0,r1} with r0 = {a.lo half, b.lo half},
// r1 = {a.hi half, b.hi half}. Used to assemble PV A-fragments in-register.
typedef struct { u32 x, y; } u32pair;
__device__ __forceinline__ u32pair swap32(u32 a, u32 b) {
#if __has_builtin(__builtin_amdgcn_permlane32_swap)
    auto r = __builtin_amdgcn_permlane32_swap((int)a, (int)b, false, false);
    u32pair o; o.x = (u32)r[0]; o.y = (u32)r[1]; return o;
#else
    const bool hi = (threadIdx.x & 32) != 0;
    u32 as = (u32)__shfl_xor((int)a, 32);
    u32 bs = (u32)__shfl_xor((int)b, 32);
    u32pair o; o.x = hi ? bs : a; o.y = hi ? b : as; return o;
#endif
}

// Async global->LDS 16B copy (global_load_lds_dwordx4).
__device__ __forceinline__ void glds16(const u16* g, u16* l) {
    __builtin_amdgcn_global_load_lds(
        (const __attribute__((address_space(1))) u32*)g,
        (__attribute__((address_space(3))) u32*)l, 16, 0, 0);
}

// ---------------------------------------------------------------------------
// Fused fp32 -> bf16 convert for all three buffers (one launch instead of 3).
// Segment sizes in 2048-elem blocks: x=4096, qkv_w=1536, proj_w=512.
// ---------------------------------------------------------------------------
__global__ __launch_bounds__(256) void cvt3(
    const float* __restrict__ a, u16* __restrict__ oa,
    const float* __restrict__ b, u16* __restrict__ ob,
    const float* __restrict__ c, u16* __restrict__ oc)
{
    const int blk = blockIdx.x;
    const float* src; u16* dst; size_t off;
    if (blk < 4096)      { src = a; dst = oa; off = (size_t)blk * 2048; }
    else if (blk < 5632) { src = b; dst = ob; off = (size_t)(blk - 4096) * 2048; }
    else                 { src = c; dst = oc; off = (size_t)(blk - 5632) * 2048; }
    const size_t i = off + (size_t)threadIdx.x * 8;
    const float4 va = *(const float4*)(src + i);
    const float4 vb = *(const float4*)(src + i + 4);
    union { u16 h[8]; uint4 v; } u;
    u.h[0] = f2bf(va.x); u.h[1] = f2bf(va.y); u.h[2] = f2bf(va.z); u.h[3] = f2bf(va.w);
    u.h[4] = f2bf(vb.x); u.h[5] = f2bf(vb.y); u.h[6] = f2bf(vb.z); u.h[7] = f2bf(vb.w);
    *(uint4*)(dst + i) = u.v;
}

// ---------------------------------------------------------------------------
// NT GEMM, m97 recipe + BK=64 + XCD swizzle (R7-verified loop) + LDS-bounce
// MODE-0 epilogue (R9).  OCC=3 for BOTH modes: R10's OCC=4 on QKV forced a
// 128-VGPR cap below the loop's ~130 peak -> scratch spills, +15 us. Reverted.
// MODE 0: fused per-head LayerNorm (q scaled by QSCALE) + scatter bf16 to
//         qkv ws [3][B][H][N][D].  MODE 1: fp32 linear [m][1024].
// ---------------------------------------------------------------------------
template<int MODE, int NJB>
__global__ __launch_bounds__(256, 3) void gemm_nt(
    const u16* __restrict__ A, const u16* __restrict__ W,
    const float* __restrict__ bias,
    const float* __restrict__ qw, const float* __restrict__ qb,
    const float* __restrict__ kw, const float* __restrict__ kb,
    void* __restrict__ outv)
{
    // sm[0]=A klo, sm[1]=A khi, sm[2]=B klo, sm[3]=B khi (32 KB total).
    // After the K-loop, reused as bounce[128][128] u16 for MODE 0.
    __shared__ __align__(16) u16 sm[4][128][32];
    const int t = threadIdx.x;
    const int w = t >> 6, lane = t & 63;
    // XCD-chunked bijective swizzle, m-fastest within chunk.
    const int nb   = blockIdx.x;
    const int cpx  = gridDim.x >> 3;
    const int nb2  = (nb & 7) * cpx + (nb >> 3);
    const int chunk = nb2 / cpx;
    const int c     = nb2 - chunk * cpx;
    const int jb  = (c >> 3) * 128;
    const int m0  = (chunk * 8 + (c & 7)) * 128;
    const int wr = (w >> 1) * 64, wc = (w & 1) * 64;
    // staging: thread t covers rows t>>2 and 64+(t>>2), k-cols (t&3)*8..+7
    const int srow = t >> 2, skc = (t & 3) * 8;
    const u16* ap0 = A + (size_t)(m0 + srow) * NK + skc;
    const u16* ap1 = ap0 + (size_t)64 * NK;
    const u16* wp0 = W + (size_t)(jb + srow) * NK + skc;
    const u16* wp1 = wp0 + (size_t)64 * NK;
    u16* asl0 = &sm[0][srow][skc];    u16* asl1 = &sm[0][srow + 64][skc];
    u16* ash0 = &sm[1][srow][skc];    u16* ash1 = &sm[1][srow + 64][skc];
    u16* bsl0 = &sm[2][srow][skc];    u16* bsl1 = &sm[2][srow + 64][skc];
    u16* bsh0 = &sm[3][srow][skc];    u16* bsh1 = &sm[3][srow + 64][skc];
    const int fm = lane & 15, fk = 8 * (lane >> 4);
    f32x4 acc[4][4];
    #pragma unroll
    for (int i = 0; i < 4; ++i)
        #pragma unroll
        for (int j = 0; j < 4; ++j) acc[i][j] = (f32x4){0.f, 0.f, 0.f, 0.f};

    for (int kt = 0; kt < NK / 64; ++kt) {
        const int ko = kt * 64;
        glds16(ap0 + ko, asl0);
        glds16(ap1 + ko, asl1);
        glds16(ap0 + ko + 32, ash0);
        glds16(ap1 + ko + 32, ash1);
        glds16(wp0 + ko, bsl0);
        glds16(wp1 + ko, bsl1);
        glds16(wp0 + ko + 32, bsh0);
        glds16(wp1 + ko + 32, bsh1);
        __syncthreads();               // drains vmcnt (glds) before reads
        {   // ---- lo k-half ----
            bf16x8 af[4], bfr[4];
            #pragma unroll
            for (int i = 0; i < 4; ++i) af[i]  = *(const bf16x8*)&sm[0][wr + 16 * i + fm][fk];
            #pragma unroll
            for (int j = 0; j < 4; ++j) bfr[j] = *(const bf16x8*)&sm[2][wc + 16 * j + fm][fk];
            #pragma unroll
            for (int i = 0; i < 4; ++i)
                #pragma unroll
                for (int j = 0; j < 4; ++j)
                    acc[i][j] = __builtin_amdgcn_mfma_f32_16x16x32_bf16(af[i], bfr[j], acc[i][j], 0, 0, 0);
        }
        {   // ---- hi k-half ----
            bf16x8 af[4], bfr[4];
            #pragma unroll
            for (int i = 0; i < 4; ++i) af[i]  = *(const bf16x8*)&sm[1][wr + 16 * i + fm][fk];
            #pragma unroll
            for (int j = 0; j < 4; ++j) bfr[j] = *(const bf16x8*)&sm[3][wc + 16 * j + fm][fk];
            #pragma unroll
            for (int i = 0; i < 4; ++i)
                #pragma unroll
                for (int j = 0; j < 4; ++j)
                    acc[i][j] = __builtin_amdgcn_mfma_f32_16x16x32_bf16(af[i], bfr[j], acc[i][j], 0, 0, 0);
        }
        __syncthreads();               // WAR before next kt's glds
    }
    // ---- epilogue ----
    const int c16 = lane & 15;
    float bv[4];
    #pragma unroll
    for (int j = 0; j < 4; ++j) bv[j] = bias[jb + wc + 16 * j + c16];
    #pragma unroll
    for (int i = 0; i < 4; ++i)
        #pragma unroll
        for (int j = 0; j < 4; ++j)
            #pragma unroll
            for (int r = 0; r < 4; ++r) acc[i][j][r] += bv[j];
    if (MODE == 0) {
        const int s = jb >> 10;            // 0=q, 1=k, 2=v (uniform per block)
        if (s < 2) {
            const float* lw = s ? kw : qw;
            const float* lb = s ? kb : qb;
            float lwv[4], lbv[4];
            #pragma unroll
            for (int j = 0; j < 4; ++j) {
                lwv[j] = lw[16 * j + c16]; lbv[j] = lb[16 * j + c16];
            }
            #pragma unroll
            for (int i = 0; i < 4; ++i)
                #pragma unroll
                for (int r = 0; r < 4; ++r) {
                    float sum = acc[i][0][r] + acc[i][1][r] + acc[i][2][r] + acc[i][3][r];
                    #pragma unroll
                    for (int off = 1; off < 16; off <<= 1) sum += __shfl_xor(sum, off);
                    const float mu = sum * (1.0f / 64.0f);
                    float v2 = 0.f;
                    #pragma unroll
                    for (int j = 0; j < 4; ++j) { const float dd = acc[i][j][r] - mu; v2 += dd * dd; }
                    #pragma unroll
                    for (int off = 1; off < 16; off <<= 1) v2 += __shfl_xor(v2, off);
                    const float rstd = rsqrtf(v2 * (1.0f / 64.0f) + 1e-5f);
                    #pragma unroll
                    for (int j = 0; j < 4; ++j) {
                        float y = (acc[i][j][r] - mu) * rstd * lwv[j] + lbv[j];
                        if (s == 0) y *= QSCALE;
                        acc[i][j][r] = y;
                    }
                }
        }
        // ---- bounce acc -> LDS [128][128] u16 (staging arrays dead) ----
        u16 (*bounce)[128] = (u16 (*)[128])sm;
        const int r0 = 4 * (lane >> 4);
        #pragma unroll
        for (int i = 0; i < 4; ++i)
            #pragma unroll
            for (int r = 0; r < 4; ++r)
                #pragma unroll
                for (int j = 0; j < 4; ++j)
                    bounce[wr + 16 * i + r0 + r][wc + 16 * j + c16] = f2bf(acc[i][j][r]);
        __syncthreads();
        // ---- coalesced store: wave covers 8 consecutive rows x 128B = 1KB ----
        u16* out = (u16*)outv;
        const int l8 = lane >> 3, k8 = lane & 7;
        #pragma unroll
        for (int ch = 0; ch < 2; ++ch) {
            const int col0 = jb + ch * 64;
            const int ss = col0 >> 10, hh = (col0 >> 6) & 15;
            #pragma unroll
            for (int g = 0; g < 4; ++g) {
                const int rr = 32 * w + 8 * g + l8;
                const int row = m0 + rr;
                const int b_ = row >> 12, n = row & 4095;
                const uint4 v = *(const uint4*)&bounce[rr][ch * 64 + k8 * 8];
                *(uint4*)&out[((((size_t)ss * NB + b_) * NH + hh) * NN + n) * ND + k8 * 8] = v;
            }
        }
    } else {
        float* out = (float*)outv;
        const int r0 = 4 * (lane >> 4);
        #pragma unroll
        for (int i = 0; i < 4; ++i)
            #pragma unroll
            for (int r = 0; r < 4; ++r) {
                const int row = m0 + wr + 16 * i + r0 + r;
                #pragma unroll
                for (int j = 0; j < 4; ++j)
                    out[(size_t)row * NC + jb + wc + 16 * j + c16] = acc[i][j][r];
            }
    }
}

// ---------------------------------------------------------------------------
// MFMA flash attention (R10-verified: ones-MFMA softmax denominator).
// L[s] = sum_k P[q,k] via mfma(pa, ONES) -- same C-row layout as O, so
// inv = 1/L[s][r] directly (replaces per-iter VALU adds + epilogue shuffles;
// denominator uses the same bf16-rounded P as the numerator).
// Block = 4 waves; wave = 64 q-rows (2 x 32-row q-sets); K-blocks of 64 keys.
// DOUBLE-BUFFERED Ks/Vt, ONE barrier/iter, T14 staging, swapped QK^T,
// in-register P via asm cvt_pk + permlane32_swap.
// ---------------------------------------------------------------------------
__global__ __launch_bounds__(256, 2) void attn_mfma(
    const u16* __restrict__ qkv, u16* __restrict__ aout)
{
    __shared__ __align__(16) u16 Ks[2][64][72];   // K-block   [key][d]   18.4 KB
    __shared__ __align__(16) u16 Vt[2][64][72];   // V-block^T [d][key]   18.4 KB
    const int bid  = blockIdx.x;
    const int qblk = bid & 15;
    const int bh   = bid >> 4;
    const int b = bh >> 4, hh = bh & 15;
    const size_t plane = (size_t)NB * NH * NN * ND;
    const size_t base  = ((size_t)(b * NH + hh)) * NN * ND;
    const u16* qp = qkv + base;
    const u16* kp = qkv + plane + base;
    const u16* vp = qkv + 2 * plane + base;
    const int t = threadIdx.x, w = t >> 6, lane = t & 63;
    const int half = lane >> 5, m32 = lane & 31;
    const int q0 = qblk * 256 + 64 * w;           // this wave's 64 q-rows

    // Q as B-operand (col = q = lane&31, k = d)
    bf16x8 qf[2][4];
    #pragma unroll
    for (int s = 0; s < 2; ++s) {
        const u16* qrow = qp + (size_t)(q0 + 32 * s + m32) * ND + 8 * half;
        #pragma unroll
        for (int kt = 0; kt < 4; ++kt) qf[s][kt] = *(const bf16x8*)(qrow + 16 * kt);
    }
    f32x16 O[2][2], L[2], z;
    #pragma unroll
    for (int r = 0; r < 16; ++r) {
        O[0][0][r] = 0.f; O[0][1][r] = 0.f;
        O[1][0][r] = 0.f; O[1][1][r] = 0.f;
        L[0][r] = 0.f;    L[1][r] = 0.f;    z[r] = 0.f;
    }
    // all-ones bf16 B-operand for the denominator MFMA (layout-independent)
    union { u32 wd[4]; bf16x8 f; } ONE1;
    #pragma unroll
    for (int i = 0; i < 4; ++i) ONE1.wd[i] = 0x3F803F80u;

    const int dgK = 16 * w;                     // K staging: key=lane, 16 d/thread
    const int kp2 = t & 31, dgV = (t >> 5) * 8; // V staging: 2 keys x 8 d/thread
    const u16* ksrc = kp + (size_t)lane * ND + dgK;
    const u16* vsrc = vp + (size_t)(2 * kp2) * ND + dgV;

    uint4 kr0, kr1, vre, vro;                   // staged regs for next K-block
    // prologue: stage block 0 into buffer 0
    kr0 = *(const uint4*)(ksrc);
    kr1 = *(const uint4*)(ksrc + 8);
    vre = *(const uint4*)(vsrc);
    vro = *(const uint4*)(vsrc + ND);
    {
        *(uint4*)&Ks[0][lane][dgK]     = kr0;
        *(uint4*)&Ks[0][lane][dgK + 8] = kr1;
        const u32* ew = (const u32*)&vre;
        const u32* ow = (const u32*)&vro;
        #pragma unroll
        for (int d = 0; d < 4; ++d) {       // v_perm_b32 pair-pack transpose
            u32 lo = __builtin_amdgcn_perm(ow[d], ew[d], 0x05040100u);
            u32 hi = __builtin_amdgcn_perm(ow[d], ew[d], 0x07060302u);
            *(u32*)&Vt[0][dgV + 2 * d][2 * kp2]     = lo;
            *(u32*)&Vt[0][dgV + 2 * d + 1][2 * kp2] = hi;
        }
    }
    __syncthreads();

    union W8 { u32 wd[4]; bf16x8 f; };

    for (int kb = 0; kb < NN / 64; ++kb) {
        const int cur = kb & 1, nxt = cur ^ 1;
        const bool more = (kb + 1) < (NN / 64);
        if (more) {   // issue next block's global loads early (hide under compute)
            const u16* ks2 = ksrc + (size_t)(kb + 1) * 64 * ND;
            kr0 = *(const uint4*)ks2;
            kr1 = *(const uint4*)(ks2 + 8);
            const u16* vs2 = vsrc + (size_t)(kb + 1) * 64 * ND;
            vre = *(const uint4*)vs2;
            vro = *(const uint4*)(vs2 + ND);
        }
        // ---- QK (s0): S^T = K . Q^T, col=lane&31=q, row=key pattern ----
        f32x16 sT0[2], sT1[2];
        __builtin_amdgcn_s_setprio(1);
        {
            bf16x8 k0 = *(const bf16x8*)&Ks[cur][m32][8 * half];
            bf16x8 k1 = *(const bf16x8*)&Ks[cur][32 + m32][8 * half];
            sT0[0] = __builtin_amdgcn_mfma_f32_32x32x16_bf16(k0, qf[0][0], z, 0, 0, 0);
            sT0[1] = __builtin_amdgcn_mfma_f32_32x32x16_bf16(k1, qf[0][0], z, 0, 0, 0);
        }
        #pragma unroll
        for (int kt = 1; kt < 4; ++kt) {
            bf16x8 k0 = *(const bf16x8*)&Ks[cur][m32][16 * kt + 8 * half];
            bf16x8 k1 = *(const bf16x8*)&Ks[cur][32 + m32][16 * kt + 8 * half];
            sT0[0] = __builtin_amdgcn_mfma_f32_32x32x16_bf16(k0, qf[0][kt], sT0[0], 0, 0, 0);
            sT0[1] = __builtin_amdgcn_mfma_f32_32x32x16_bf16(k1, qf[0][kt], sT0[1], 0, 0, 0);
        }
        // ---- QK (s1): issues while sT0 chain drains ----
        {
            bf16x8 k0 = *(const bf16x8*)&Ks[cur][m32][8 * half];
            bf16x8 k1 = *(const bf16x8*)&Ks[cur][32 + m32][8 * half];
            sT1[0] = __builtin_amdgcn_mfma_f32_32x32x16_bf16(k0, qf[1][0], z, 0, 0, 0);
            sT1[1] = __builtin_amdgcn_mfma_f32_32x32x16_bf16(k1, qf[1][0], z, 0, 0, 0);
        }
        #pragma unroll
        for (int kt = 1; kt < 4; ++kt) {
            bf16x8 k0 = *(const bf16x8*)&Ks[cur][m32][16 * kt + 8 * half];
            bf16x8 k1 = *(const bf16x8*)&Ks[cur][32 + m32][16 * kt + 8 * half];
            sT1[0] = __builtin_amdgcn_mfma_f32_32x32x16_bf16(k0, qf[1][kt], sT1[0], 0, 0, 0);
            sT1[1] = __builtin_amdgcn_mfma_f32_32x32x16_bf16(k1, qf[1][kt], sT1[1], 0, 0, 0);
        }
        __builtin_amdgcn_s_setprio(0);
        // ---- SM (s0): exp2 + cvt_pk + permlane, under QK(s1) MFMAs ----
        W8 pa0[4], pa1[4];
        #pragma unroll
        for (int kh = 0; kh < 2; ++kh) {
            float p[16];
            #pragma unroll
            for (int r = 0; r < 16; ++r) p[r] = fast_exp2(sT0[kh][r]);
            u32 c[4][2];
            #pragma unroll
            for (int g = 0; g < 4; ++g) {
                c[g][0] = pkbf(p[4 * g + 0], p[4 * g + 1]);
                c[g][1] = pkbf(p[4 * g + 2], p[4 * g + 3]);
            }
            #pragma unroll
            for (int par = 0; par < 2; ++par) {
                u32pair wA = swap32(c[2 * par][0], c[2 * par + 1][0]);
                u32pair wB = swap32(c[2 * par][1], c[2 * par + 1][1]);
                const int kt = 2 * kh + par;
                pa0[kt].wd[0] = wA.x;   // keys +0,+1 (from low-half lane)
                pa0[kt].wd[1] = wB.x;   // keys +2,+3
                pa0[kt].wd[2] = wA.y;   // keys +4,+5 (from high-half lane)
                pa0[kt].wd[3] = wB.y;   // keys +6,+7
            }
        }
        // ---- PV (s0) + denominator L[0] ----
        __builtin_amdgcn_s_setprio(1);
        #pragma unroll
        for (int kt = 0; kt < 4; ++kt) {
            bf16x8 v0 = *(const bf16x8*)&Vt[cur][m32][16 * kt + 8 * half];
            bf16x8 v1 = *(const bf16x8*)&Vt[cur][32 + m32][16 * kt + 8 * half];
            O[0][0] = __builtin_amdgcn_mfma_f32_32x32x16_bf16(pa0[kt].f, v0, O[0][0], 0, 0, 0);
            O[0][1] = __builtin_amdgcn_mfma_f32_32x32x16_bf16(pa0[kt].f, v1, O[0][1], 0, 0, 0);
            L[0]    = __builtin_amdgcn_mfma_f32_32x32x16_bf16(pa0[kt].f, ONE1.f, L[0], 0, 0, 0);
        }
        __builtin_amdgcn_s_setprio(0);
        // ---- SM (s1): under PV(s0) MFMAs ----
        #pragma unroll
        for (int kh = 0; kh < 2; ++kh) {
            float p[16];
            #pragma unroll
            for (int r = 0; r < 16; ++r) p[r] = fast_exp2(sT1[kh][r]);
            u32 c[4][2];
            #pragma unroll
            for (int g = 0; g < 4; ++g) {
                c[g][0] = pkbf(p[4 * g + 0], p[4 * g + 1]);
                c[g][1] = pkbf(p[4 * g + 2], p[4 * g + 3]);
            }
            #pragma unroll
            for (int par = 0; par < 2; ++par) {
                u32pair wA = swap32(c[2 * par][0], c[2 * par + 1][0]);
                u32pair wB = swap32(c[2 * par][1], c[2 * par + 1][1]);
                const int kt = 2 * kh + par;
                pa1[kt].wd[0] = wA.x;
                pa1[kt].wd[1] = wB.x;
                pa1[kt].wd[2] = wA.y;
                pa1[kt].wd[3] = wB.y;
            }
        }
        // ---- PV (s1) + denominator L[1] ----
        __builtin_amdgcn_s_setprio(1);
        #pragma unroll
        for (int kt = 0; kt < 4; ++kt) {
            bf16x8 v0 = *(const bf16x8*)&Vt[cur][m32][16 * kt + 8 * half];
            bf16x8 v1 = *(const bf16x8*)&Vt[cur][32 + m32][16 * kt + 8 * half];
            O[1][0] = __builtin_amdgcn_mfma_f32_32x32x16_bf16(pa1[kt].f, v0, O[1][0], 0, 0, 0);
            O[1][1] = __builtin_amdgcn_mfma_f32_32x32x16_bf16(pa1[kt].f, v1, O[1][1], 0, 0, 0);
            L[1]    = __builtin_amdgcn_mfma_f32_32x32x16_bf16(pa1[kt].f, ONE1.f, L[1], 0, 0, 0);
        }
        __builtin_amdgcn_s_setprio(0);
        // ---- stage next block into nxt buffer; ONE barrier per iteration ----
        if (more) {
            *(uint4*)&Ks[nxt][lane][dgK]     = kr0;
            *(uint4*)&Ks[nxt][lane][dgK + 8] = kr1;
            const u32* ew = (const u32*)&vre;
            const u32* ow = (const u32*)&vro;
            #pragma unroll
            for (int d = 0; d < 4; ++d) {
                u32 lo = __builtin_amdgcn_perm(ow[d], ew[d], 0x05040100u);
                u32 hi = __builtin_amdgcn_perm(ow[d], ew[d], 0x07060302u);
                *(u32*)&Vt[nxt][dgV + 2 * d][2 * kp2]     = lo;
                *(u32*)&Vt[nxt][dgV + 2 * d + 1][2 * kp2] = hi;
            }
            __syncthreads();   // nxt writes visible; cur reads done for all waves
        }
    }
    // epilogue: L has the SAME C-row layout as O -> direct per-reg normalize.
    #pragma unroll
    for (int s = 0; s < 2; ++s) {
        #pragma unroll
        for (int r = 0; r < 16; ++r) {
            const int qq = (r & 3) + 8 * (r >> 2) + 4 * half;   // O-row for this reg
            const float inv = 1.0f / L[s][r];
            const int row = q0 + 32 * s + qq;
            u16* dst = aout + ((size_t)(b * NN + row)) * NC + hh * 64;
            dst[m32]      = f2bf(O[s][0][r] * inv);
            dst[32 + m32] = f2bf(O[s][1][r] * inv);
        }
    }
}

// ---------------------------------------------------------------------------
extern "C" void kernel_launch(void* const* d_in, const int* in_sizes, int n_in,
                              void* d_out, int out_size, void* d_ws, size_t ws_size,
                              hipStream_t stream) {
    const float* x     = (const float*)d_in[0];
    const float* qkv_w = (const float*)d_in[1];
    const float* qkv_b = (const float*)d_in[2];
    const float* q_nw  = (const float*)d_in[3];
    const float* q_nb  = (const float*)d_in[4];
    const float* k_nw  = (const float*)d_in[5];
    const float* k_nb  = (const float*)d_in[6];
    const float* p_w   = (const float*)d_in[7];
    const float* p_b   = (const float*)d_in[8];
    float* out = (float*)d_out;               // fp32 output
    // ws layout (u16 elements):
    //   qkv   [3][B][H][N][D]                              48 MB
    //   x_bf / attn_o (aliased: x_bf dead after QKV GEMM)  16.8 MB
    //   w_bf  qkv_w bf16                                    6.3 MB
    //   pw_bf proj_w bf16                                   2.1 MB
    u16* qkv    = (u16*)d_ws;
    u16* x_bf   = qkv + (size_t)3 * NB * NH * NN * ND;
    u16* attn_o = x_bf;                        // alias
    u16* w_bf   = x_bf + (size_t)NM * NC;
    u16* pw_bf  = w_bf + (size_t)J_QKV * NK;

    cvt3<<<6144, 256, 0, stream>>>(x, x_bf, qkv_w, w_bf, p_w, pw_bf);

    // 1D grids (both % 8 == 0) with in-kernel bijective XCD-chunk swizzle.
    gemm_nt<0, J_QKV / 128><<<(J_QKV / 128) * (NM / 128), 256, 0, stream>>>(
        x_bf, w_bf, qkv_b, q_nw, q_nb, k_nw, k_nb, qkv);
    attn_mfma<<<NB * NH * (NN / 256), 256, 0, stream>>>(qkv, attn_o);
    gemm_nt<1, NC / 128><<<(NC / 128) * (NM / 128), 256, 0, stream>>>(
        attn_o, pw_bf, p_b, q_nw, q_nb, k_nw, k_nb, out);
}